// Round 1
// baseline (840.668 us; speedup 1.0000x reference)
//
#include <hip/hip_runtime.h>
#include <math.h>

#define K_DIM 8192     // S*DIM
#define D_DIM 2048
#define M_ROWS 8192
#define N_W 32         // W columns (only 24 used)
#define NC 24          // used columns of H
#define BK 256         // K-chunk staged in LDS

// ---------------------------------------------------------------------------
// Kernel 1: per-row params.
//   H[m, 0:24] = X[m, :] @ W[:, 0:24]
//   lanes 0..15 : p = exp(a_res*H + b_res)  -> 20-iter Sinkhorn on 4x4
//   lanes 16..23: a*sigmoid(H) + b   (pre: 16..19, pos: 20..23)
//   params[m*24 + n] written for n<24.
// Block = 256 threads (4 waves); each wave owns 4 rows; block owns 16 rows.
// W chunk [BK][32] staged in LDS with XOR swizzle col' = col ^ (((k>>2)&7)<<2)
// so both staging writes and per-lane ds_read_b128 are 2-way (free).
// ---------------------------------------------------------------------------
__global__ __launch_bounds__(256) void mhc_params_kernel(
    const float* __restrict__ X, const float* __restrict__ W,
    const float* __restrict__ ab, float* __restrict__ params)
{
    __shared__ float Wlds[BK * 32];
    const int t = threadIdx.x;
    const int lane = t & 63;
    const int wave = t >> 6;
    const int rowbase = blockIdx.x * 16 + wave * 4;

    float acc[4][NC];
#pragma unroll
    for (int r = 0; r < 4; ++r)
#pragma unroll
        for (int n = 0; n < NC; ++n) acc[r][n] = 0.f;

    const float4* __restrict__ Wg = reinterpret_cast<const float4*>(W);
    const float4* __restrict__ Xg = reinterpret_cast<const float4*>(X);

    for (int c = 0; c < K_DIM / BK; ++c) {
        // ---- stage W chunk [BK][32] (32 KB), coalesced, swizzled ----
#pragma unroll
        for (int q = 0; q < 8; ++q) {
            int f   = t + 256 * q;            // float4 index in chunk, 0..2047
            int kl  = f >> 3;                 // k row within chunk
            int col = (f & 7) << 2;           // starting column (multiple of 4)
            int scol = col ^ (((kl >> 2) & 7) << 2);
            float4 v = Wg[(size_t)c * (BK * (N_W / 4)) + f];
            *reinterpret_cast<float4*>(&Wlds[kl * N_W + scol]) = v;
        }
        __syncthreads();

        // ---- compute: lane owns k = 4*lane + j (j=0..3) of this chunk ----
        float4 xv[4];
#pragma unroll
        for (int r = 0; r < 4; ++r)
            xv[r] = Xg[(size_t)(rowbase + r) * (K_DIM / 4) + c * (BK / 4) + lane];

        const int sw = (lane & 7) << 2;       // ((k>>2)&7)<<2 with k=4*lane+j
#pragma unroll
        for (int j = 0; j < 4; ++j) {
            const int k = 4 * lane + j;
            float4 w[6];
#pragma unroll
            for (int u = 0; u < 6; ++u)
                w[u] = *reinterpret_cast<const float4*>(&Wlds[k * N_W + ((u * 4) ^ sw)]);
#pragma unroll
            for (int r = 0; r < 4; ++r) {
                const float x = reinterpret_cast<const float*>(&xv[r])[j];
#pragma unroll
                for (int u = 0; u < 6; ++u) {
                    acc[r][u * 4 + 0] = fmaf(x, w[u].x, acc[r][u * 4 + 0]);
                    acc[r][u * 4 + 1] = fmaf(x, w[u].y, acc[r][u * 4 + 1]);
                    acc[r][u * 4 + 2] = fmaf(x, w[u].z, acc[r][u * 4 + 2]);
                    acc[r][u * 4 + 3] = fmaf(x, w[u].w, acc[r][u * 4 + 3]);
                }
            }
        }
        __syncthreads();
    }

    // ---- per-row: cross-lane reduce, transform, sinkhorn, store ----
    const float bias  = (lane < NC) ? ab[lane] : 0.f;
    const float scale = ab[(lane < 16) ? 24 : ((lane < 20) ? 25 : 26)];

    for (int r = 0; r < 4; ++r) {
        float pl = 0.f;
#pragma unroll
        for (int n = 0; n < NC; ++n) {
            float v = acc[r][n];
            v += __shfl_xor(v, 32);
            v += __shfl_xor(v, 16);
            v += __shfl_xor(v, 8);
            v += __shfl_xor(v, 4);
            v += __shfl_xor(v, 2);
            v += __shfl_xor(v, 1);
            if (lane == n) pl = v;   // lane n holds H[row, n]
        }

        float vout;
        if (lane < 16) {
            vout = __expf(fmaf(scale, pl, bias));            // exp(a_res*H + b_res)
        } else {
            vout = fmaf(scale, 1.f / (1.f + __expf(-pl)), bias);  // a*sigmoid(H)+b
        }

        // Sinkhorn on lanes 0..15: lane = s*4 + i; rows share (lane>>2),
        // cols share (lane&3). axis=-1 sum = xor 1,2 ; axis=-2 sum = xor 4,8.
        float p = vout;
        for (int it = 0; it < 20; ++it) {
            float rs = p + __shfl_xor(p, 1);
            rs += __shfl_xor(rs, 2);
            p = p / rs;
            float cs = p + __shfl_xor(p, 4);
            cs += __shfl_xor(cs, 8);
            p = p / cs;
        }

        const float res = (lane < 16) ? p : vout;
        if (lane < NC)
            params[(size_t)(rowbase + r) * NC + lane] = res;
    }
}

// ---------------------------------------------------------------------------
// Kernel 2: apply. One block (256 threads) per row, float4 streaming.
//   Y[d]      = sum_i Hpre[i] * X[row, i*2048 + d]
//   O[s][d]   = sum_i Hres[s][i] * X[row, i*2048 + d] + Hpos[s]*Y[d]
// ---------------------------------------------------------------------------
__global__ __launch_bounds__(256) void mhc_apply_kernel(
    const float* __restrict__ X, const float* __restrict__ params,
    float* __restrict__ out)
{
    const int row = blockIdx.x;
    const int t = threadIdx.x;
    const float* __restrict__ p = params + (size_t)row * NC;

    float hres[4][4], hpre[4], hpos[4];
#pragma unroll
    for (int i = 0; i < 16; ++i) hres[i >> 2][i & 3] = p[i];
#pragma unroll
    for (int i = 0; i < 4; ++i) hpre[i] = p[16 + i];
#pragma unroll
    for (int i = 0; i < 4; ++i) hpos[i] = p[20 + i];

    const float4* __restrict__ Xr =
        reinterpret_cast<const float4*>(X + (size_t)row * K_DIM);
    float4* __restrict__ Or = reinterpret_cast<float4*>(out + (size_t)row * K_DIM);

#pragma unroll
    for (int q = 0; q < 2; ++q) {
        const int pos = t + q * 256;          // float4 index within a 2048-seg
        float4 xq[4];
#pragma unroll
        for (int i = 0; i < 4; ++i) xq[i] = Xr[i * (D_DIM / 4) + pos];

        float y[4];
#pragma unroll
        for (int e = 0; e < 4; ++e) {
            float s = 0.f;
#pragma unroll
            for (int i = 0; i < 4; ++i)
                s = fmaf(hpre[i], reinterpret_cast<const float*>(&xq[i])[e], s);
            y[e] = s;
        }

#pragma unroll
        for (int s = 0; s < 4; ++s) {
            float4 o;
            float* oe = reinterpret_cast<float*>(&o);
#pragma unroll
            for (int e = 0; e < 4; ++e) {
                float v = hpos[s] * y[e];
#pragma unroll
                for (int i = 0; i < 4; ++i)
                    v = fmaf(hres[s][i], reinterpret_cast<const float*>(&xq[i])[e], v);
                oe[e] = v;
            }
            Or[s * (D_DIM / 4) + pos] = o;
        }
    }
}

extern "C" void kernel_launch(void* const* d_in, const int* in_sizes, int n_in,
                              void* d_out, int out_size, void* d_ws, size_t ws_size,
                              hipStream_t stream) {
    const float* X  = (const float*)d_in[0];
    const float* W  = (const float*)d_in[1];
    const float* ab = (const float*)d_in[2];
    float* out = (float*)d_out;
    float* params = (float*)d_ws;   // needs M_ROWS*NC*4 = 786432 bytes

    mhc_params_kernel<<<M_ROWS / 16, 256, 0, stream>>>(X, W, ab, params);
    mhc_apply_kernel<<<M_ROWS, 256, 0, stream>>>(X, params, out);
}

// Round 2
// 208.835 us; speedup vs baseline: 4.0255x; 4.0255x over previous
//
#include <hip/hip_runtime.h>
#include <math.h>

#define K_DIM 8192     // S*DIM
#define D_DIM 2048
#define M_ROWS 8192
#define N_W 32         // W columns (only 24 used)
#define NC 24          // used columns of H
#define BK 256         // K-chunk staged in LDS
#define ROWS_PER_WAVE 2
#define ROWS_PER_BLOCK (ROWS_PER_WAVE * 4)

// ---------------------------------------------------------------------------
// Kernel 1: per-row params.
//   H[m, 0:24] = X[m, :] @ W[:, 0:24]
//   lanes 0..15 : p = exp(a_res*H + b_res)  -> 20-iter Sinkhorn on 4x4
//   lanes 16..23: a*sigmoid(H) + b   (pre: 16..19, pos: 20..23)
// Block = 256 threads (4 waves); each wave owns 2 rows (acc = 48 VGPRs,
// no spill). W chunk [BK][32] staged in LDS with XOR swizzle
// col' = col ^ (((k>>2)&7)<<2) so staging writes and ds_read_b128 are
// conflict-free (2-way = free).
// ---------------------------------------------------------------------------
__global__ __launch_bounds__(256) void mhc_params_kernel(
    const float* __restrict__ X, const float* __restrict__ W,
    const float* __restrict__ ab, float* __restrict__ params)
{
    __shared__ float Wlds[BK * 32];
    const int t = threadIdx.x;
    const int lane = t & 63;
    const int wave = t >> 6;
    const int rowbase = blockIdx.x * ROWS_PER_BLOCK + wave * ROWS_PER_WAVE;

    float acc[ROWS_PER_WAVE][NC];
#pragma unroll
    for (int r = 0; r < ROWS_PER_WAVE; ++r)
#pragma unroll
        for (int n = 0; n < NC; ++n) acc[r][n] = 0.f;

    const float4* __restrict__ Wg = reinterpret_cast<const float4*>(W);
    const float4* __restrict__ Xg = reinterpret_cast<const float4*>(X);

    for (int c = 0; c < K_DIM / BK; ++c) {
        // ---- stage W chunk [BK][32] (32 KB), coalesced, swizzled ----
#pragma unroll
        for (int q = 0; q < 8; ++q) {
            int f   = t + 256 * q;            // float4 index in chunk, 0..2047
            int kl  = f >> 3;                 // k row within chunk
            int col = (f & 7) << 2;           // starting column (multiple of 4)
            int scol = col ^ (((kl >> 2) & 7) << 2);
            float4 v = Wg[(size_t)c * (BK * (N_W / 4)) + f];
            *reinterpret_cast<float4*>(&Wlds[kl * N_W + scol]) = v;
        }
        __syncthreads();

        // ---- compute: lane owns k = 4*lane + j (j=0..3) of this chunk ----
        float4 xv[ROWS_PER_WAVE];
#pragma unroll
        for (int r = 0; r < ROWS_PER_WAVE; ++r)
            xv[r] = Xg[(size_t)(rowbase + r) * (K_DIM / 4) + c * (BK / 4) + lane];

        const int sw = (lane & 7) << 2;       // ((k>>2)&7)<<2 with k=4*lane+j
#pragma unroll
        for (int j = 0; j < 4; ++j) {
            const int k = 4 * lane + j;
#pragma unroll
            for (int u = 0; u < 6; ++u) {
                const float4 w = *reinterpret_cast<const float4*>(
                    &Wlds[k * N_W + ((u * 4) ^ sw)]);
#pragma unroll
                for (int r = 0; r < ROWS_PER_WAVE; ++r) {
                    const float x = reinterpret_cast<const float*>(&xv[r])[j];
                    acc[r][u * 4 + 0] = fmaf(x, w.x, acc[r][u * 4 + 0]);
                    acc[r][u * 4 + 1] = fmaf(x, w.y, acc[r][u * 4 + 1]);
                    acc[r][u * 4 + 2] = fmaf(x, w.z, acc[r][u * 4 + 2]);
                    acc[r][u * 4 + 3] = fmaf(x, w.w, acc[r][u * 4 + 3]);
                }
            }
        }
        __syncthreads();
    }

    // ---- per-row: cross-lane reduce, transform, sinkhorn, store ----
    const float bias  = (lane < NC) ? ab[lane] : 0.f;
    const float scale = ab[(lane < 16) ? 24 : ((lane < 20) ? 25 : 26)];

    for (int r = 0; r < ROWS_PER_WAVE; ++r) {
        float pl = 0.f;
#pragma unroll
        for (int n = 0; n < NC; ++n) {
            float v = acc[r][n];
            v += __shfl_xor(v, 32);
            v += __shfl_xor(v, 16);
            v += __shfl_xor(v, 8);
            v += __shfl_xor(v, 4);
            v += __shfl_xor(v, 2);
            v += __shfl_xor(v, 1);
            if (lane == n) pl = v;   // lane n holds H[row, n]
        }

        float vout;
        if (lane < 16) {
            vout = __expf(fmaf(scale, pl, bias));            // exp(a_res*H + b_res)
        } else {
            vout = fmaf(scale, 1.f / (1.f + __expf(-pl)), bias);  // a*sigmoid(H)+b
        }

        // Sinkhorn on lanes 0..15: lane = s*4 + i; rows share (lane>>2),
        // cols share (lane&3). axis=-1 sum = xor 1,2 ; axis=-2 sum = xor 4,8.
        float p = vout;
        for (int it = 0; it < 20; ++it) {
            float rs = p + __shfl_xor(p, 1);
            rs += __shfl_xor(rs, 2);
            p = p / rs;
            float cs = p + __shfl_xor(p, 4);
            cs += __shfl_xor(cs, 8);
            p = p / cs;
        }

        const float res = (lane < 16) ? p : vout;
        if (lane < NC)
            params[(size_t)(rowbase + r) * NC + lane] = res;
    }
}

// ---------------------------------------------------------------------------
// Kernel 2: apply. One block (256 threads) per row, float4 streaming.
//   Y[d]      = sum_i Hpre[i] * X[row, i*2048 + d]
//   O[s][d]   = sum_i Hres[s][i] * X[row, i*2048 + d] + Hpos[s]*Y[d]
// ---------------------------------------------------------------------------
__global__ __launch_bounds__(256) void mhc_apply_kernel(
    const float* __restrict__ X, const float* __restrict__ params,
    float* __restrict__ out)
{
    const int row = blockIdx.x;
    const int t = threadIdx.x;
    const float* __restrict__ p = params + (size_t)row * NC;

    float hres[4][4], hpre[4], hpos[4];
#pragma unroll
    for (int i = 0; i < 16; ++i) hres[i >> 2][i & 3] = p[i];
#pragma unroll
    for (int i = 0; i < 4; ++i) hpre[i] = p[16 + i];
#pragma unroll
    for (int i = 0; i < 4; ++i) hpos[i] = p[20 + i];

    const float4* __restrict__ Xr =
        reinterpret_cast<const float4*>(X + (size_t)row * K_DIM);
    float4* __restrict__ Or = reinterpret_cast<float4*>(out + (size_t)row * K_DIM);

#pragma unroll
    for (int q = 0; q < 2; ++q) {
        const int pos = t + q * 256;          // float4 index within a 2048-seg
        float4 xq[4];
#pragma unroll
        for (int i = 0; i < 4; ++i) xq[i] = Xr[i * (D_DIM / 4) + pos];

        float y[4];
#pragma unroll
        for (int e = 0; e < 4; ++e) {
            float s = 0.f;
#pragma unroll
            for (int i = 0; i < 4; ++i)
                s = fmaf(hpre[i], reinterpret_cast<const float*>(&xq[i])[e], s);
            y[e] = s;
        }

#pragma unroll
        for (int s = 0; s < 4; ++s) {
            float4 o;
            float* oe = reinterpret_cast<float*>(&o);
#pragma unroll
            for (int e = 0; e < 4; ++e) {
                float v = hpos[s] * y[e];
#pragma unroll
                for (int i = 0; i < 4; ++i)
                    v = fmaf(hres[s][i], reinterpret_cast<const float*>(&xq[i])[e], v);
                oe[e] = v;
            }
            Or[s * (D_DIM / 4) + pos] = o;
        }
    }
}

extern "C" void kernel_launch(void* const* d_in, const int* in_sizes, int n_in,
                              void* d_out, int out_size, void* d_ws, size_t ws_size,
                              hipStream_t stream) {
    const float* X  = (const float*)d_in[0];
    const float* W  = (const float*)d_in[1];
    const float* ab = (const float*)d_in[2];
    float* out = (float*)d_out;
    float* params = (float*)d_ws;   // needs M_ROWS*NC*4 = 786432 bytes

    mhc_params_kernel<<<M_ROWS / ROWS_PER_BLOCK, 256, 0, stream>>>(X, W, ab, params);
    mhc_apply_kernel<<<M_ROWS, 256, 0, stream>>>(X, params, out);
}